// Round 16
// baseline (541.142 us; speedup 1.0000x reference)
//
// Round 16: fifth resubmit of the round-11 kernel. Rounds 11-15 all died to
// container disk-full before the kernel could compile or run (r11: LLVM output
// write; r12: ref-npz write; r13: .cpp push; r14/r15: test .py push). The
// design has never executed. Protocol from r5->r6 (disk-full then clean run of
// identical source after pod recovery): resubmit unchanged for attribution.
//
// Design: grid-2048 kv_attn (bt x s-quarter), atomic num/den combine.
// r10 lesson: occupancy was GRID-capped (512 blocks = 2/CU); (256,3) then
// spilled for unreachable occupancy. Now: 8 blocks/CU available, reg diet
// (qn reloaded per epilogue, b in 2x4 groups) -> peak ~125 regs, no spill.
#include <hip/hip_runtime.h>
#include <hip/hip_bf16.h>

#define SOFTCAP_ 50.0f
#define EPS_ 1e-6f

typedef __attribute__((ext_vector_type(8))) short bf16x8;
typedef __attribute__((ext_vector_type(4))) float f32x4;

__device__ __forceinline__ unsigned short f2bf(float f) {
    unsigned u = __float_as_uint(f);
    u += 0x7FFFu + ((u >> 16) & 1u);
    return (unsigned short)(u >> 16);
}

// ---------------- Wkv -> bf16 fragment-layout swizzle ----------------
// layout: [kb(32)][nb(32)][lane(64)][j(8)]  value = W'[kb*32+(l>>4)*8+j][nb*16+(l&15)]
// n<256 -> Wk col n ; n>=256 -> Wv col n-256
__global__ void wkv_swizzle(const float* __restrict__ Wk, const float* __restrict__ Wv,
                            unsigned short* __restrict__ wkv) {
    int tid = blockIdx.x * 256 + threadIdx.x;   // 0..65535
    int l = tid & 63;
    int nb = (tid >> 6) & 31;
    int kb = tid >> 11;
    int n = nb * 16 + (l & 15);
    int kbase = kb * 32 + ((l >> 4) << 3);
    const float* src = (n < 256) ? (Wk + n) : (Wv + (n - 256));
    unsigned short r[8];
#pragma unroll
    for (int j = 0; j < 8; ++j) r[j] = f2bf(src[(size_t)(kbase + j) * 256]);
    uint4 o;
    o.x = (unsigned)r[0] | ((unsigned)r[1] << 16);
    o.y = (unsigned)r[2] | ((unsigned)r[3] << 16);
    o.z = (unsigned)r[4] | ((unsigned)r[5] << 16);
    o.w = (unsigned)r[6] | ((unsigned)r[7] << 16);
    *(uint4*)(wkv + (size_t)tid * 8) = o;
}

// ---------------- Q projection + RMSNorm ----------------
__global__ __launch_bounds__(256) void qproj_kernel(
    const float* __restrict__ agent, const float* __restrict__ Wq,
    const float* __restrict__ q_gamma, float* __restrict__ ws_q)
{
    __shared__ float srows[8][1024];
    int cg = blockIdx.x, rg = blockIdx.y;
    int t = threadIdx.x;
#pragma unroll
    for (int j = 0; j < 8; ++j) {
        int f = j * 256 + t;
        int row = f >> 8, c4 = f & 255;
        *(float4*)&srows[row][c4 * 4] =
            *(const float4*)(agent + (size_t)(rg * 8 + row) * 1024 + c4 * 4);
    }
    __syncthreads();
    int c = cg * 64 + (t & 63);
    int rq = t >> 6;
    float acc0 = 0.f, acc1 = 0.f;
    for (int k = 0; k < 1024; k += 4) {
        float w0 = Wq[(size_t)(k + 0) * 1024 + c];
        float w1 = Wq[(size_t)(k + 1) * 1024 + c];
        float w2 = Wq[(size_t)(k + 2) * 1024 + c];
        float w3 = Wq[(size_t)(k + 3) * 1024 + c];
        float4 a0 = *(const float4*)&srows[rq * 2][k];
        float4 a1 = *(const float4*)&srows[rq * 2 + 1][k];
        acc0 += a0.x * w0 + a0.y * w1 + a0.z * w2 + a0.w * w3;
        acc1 += a1.x * w0 + a1.y * w1 + a1.z * w2 + a1.w * w3;
    }
    float g = q_gamma[t & 63];
    float ss0 = acc0 * acc0, ss1 = acc1 * acc1;
#pragma unroll
    for (int d = 1; d < 64; d <<= 1) { ss0 += __shfl_xor(ss0, d); ss1 += __shfl_xor(ss1, d); }
    float rs0 = rsqrtf(ss0 * (1.0f / 64.0f) + EPS_);
    float rs1 = rsqrtf(ss1 * (1.0f / 64.0f) + EPS_);
    ws_q[(size_t)(rg * 8 + rq * 2 + 0) * 1024 + c] = acc0 * rs0 * g;
    ws_q[(size_t)(rg * 8 + rq * 2 + 1) * 1024 + c] = acc1 * rs1 * g;
}

// ---------------- Fused KV projection + attention (grid 2048, atomic combine) ----------------
// block = (bt, s-quarter of 64 rows); 4 waves = 4 kv-heads; wave does K scores AND V
// for its head over 2 sub-chunks of 32 rows (in-wave math, r6/r10-proven).
// Partial num/den atomically added to att_raw / den (softcap => plain sums, associative).
__global__ __launch_bounds__(256, 3) void kv_attn_kernel(
    const float* __restrict__ z, const unsigned short* __restrict__ wkv,
    const float* __restrict__ ws_q, const float* __restrict__ k_gamma,
    float* __restrict__ att_raw, float* __restrict__ den)
{
    __shared__ __align__(16) unsigned short zlds[32 * 256];   // 16 KB, XOR-swizzled bf16
    const int blk = blockIdx.x;
    const int bt = blk >> 2, q = blk & 3;  // s-quarter q: rows bt*256 + q*64 ..
    const int tid = threadIdx.x;
    const int head = tid >> 6;             // wave = kv head 0..3
    const int l = tid & 63, l15 = l & 15, lg = l >> 4;

    float kgm[4];
#pragma unroll
    for (int ni = 0; ni < 4; ++ni) kgm[ni] = k_gamma[ni * 16 + l15];

    float out_acc[4][4] = {};
    float denom[4] = {};

    for (int sc = 0; sc < 2; ++sc) {       // 2 sub-chunks of 32 s-rows
        f32x4 acc[2][8];
#pragma unroll
        for (int mi = 0; mi < 2; ++mi)
#pragma unroll
            for (int ni = 0; ni < 8; ++ni) acc[mi][ni] = (f32x4){0.f, 0.f, 0.f, 0.f};

        for (int sl = 0; sl < 4; ++sl) {   // k-slices of 256
            __syncthreads();               // prior reads of zlds done
#pragma unroll
            for (int jb = 0; jb < 2; ++jb) {   // stage 32x256 fp32 -> bf16 (8 float4/thr)
                float4 v[4];
#pragma unroll
                for (int i = 0; i < 4; ++i) {
                    int f = (jb * 4 + i) * 256 + tid;   // float4 idx 0..2047
                    int row = f >> 6, c4 = f & 63;
                    v[i] = *(const float4*)(z + (size_t)(bt * 256 + q * 64 + sc * 32 + row) * 1024
                                              + sl * 256 + c4 * 4);
                }
#pragma unroll
                for (int i = 0; i < 4; ++i) {
                    int f = (jb * 4 + i) * 256 + tid;
                    int row = f >> 6, c4 = f & 63;
                    unsigned lo = (unsigned)f2bf(v[i].x) | ((unsigned)f2bf(v[i].y) << 16);
                    unsigned hi = (unsigned)f2bf(v[i].z) | ((unsigned)f2bf(v[i].w) << 16);
                    int byteoff = ((row * 512) + c4 * 8) ^ ((row & 7) << 4);
                    *(uint2*)((char*)zlds + byteoff) = (uint2){lo, hi};
                }
            }
            __syncthreads();               // stage visible
#pragma unroll
            for (int ksl = 0; ksl < 8; ++ksl) {
                const int kb = sl * 8 + ksl;
                int boff0 = ((l15 * 512) + ksl * 64 + lg * 16) ^ ((l15 & 7) << 4);
                bf16x8 a0 = *(const bf16x8*)((const char*)zlds + boff0);
                bf16x8 a1 = *(const bf16x8*)((const char*)zlds + boff0 + 8192); // row+16: same swizzle
                // K group (nb = head*4+ni), then V group (nb = 16+head*4+ni): peak live b = 4
                bf16x8 bk[4];
#pragma unroll
                for (int ni = 0; ni < 4; ++ni)
                    bk[ni] = *(const bf16x8*)(wkv + ((size_t)(kb * 32 + head * 4 + ni) * 64 + l) * 8);
#pragma unroll
                for (int ni = 0; ni < 4; ++ni) {
                    acc[0][ni] = __builtin_amdgcn_mfma_f32_16x16x32_bf16(a0, bk[ni], acc[0][ni], 0, 0, 0);
                    acc[1][ni] = __builtin_amdgcn_mfma_f32_16x16x32_bf16(a1, bk[ni], acc[1][ni], 0, 0, 0);
                }
                bf16x8 bv[4];
#pragma unroll
                for (int ni = 0; ni < 4; ++ni)
                    bv[ni] = *(const bf16x8*)(wkv + ((size_t)(kb * 32 + 16 + head * 4 + ni) * 64 + l) * 8);
#pragma unroll
                for (int ni = 0; ni < 4; ++ni) {
                    acc[0][4 + ni] = __builtin_amdgcn_mfma_f32_16x16x32_bf16(a0, bv[ni], acc[0][4 + ni], 0, 0, 0);
                    acc[1][4 + ni] = __builtin_amdgcn_mfma_f32_16x16x32_bf16(a1, bv[ni], acc[1][4 + ni], 0, 0, 0);
                }
            }
        }
        // ---- in-wave attention epilogue for this sub-chunk's 32 rows ----
        float qn[4][4];                    // reloaded per epilogue (L2-hot) - not persistent
#pragma unroll
        for (int g = 0; g < 4; ++g)
#pragma unroll
            for (int ni = 0; ni < 4; ++ni)
                qn[g][ni] = ws_q[(size_t)bt * 1024 + (head * 4 + g) * 64 + ni * 16 + l15];
#pragma unroll
        for (int mi = 0; mi < 2; ++mi) {
#pragma unroll
            for (int r = 0; r < 4; ++r) {
                float k0 = acc[mi][0][r], k1 = acc[mi][1][r], k2 = acc[mi][2][r], k3 = acc[mi][3][r];
                float ss = k0 * k0 + k1 * k1 + k2 * k2 + k3 * k3;
                ss += __shfl_xor(ss, 1); ss += __shfl_xor(ss, 2);
                ss += __shfl_xor(ss, 4); ss += __shfl_xor(ss, 8);
                float rs = rsqrtf(ss * (1.0f / 64.0f) + EPS_);
                k0 *= rs * kgm[0]; k1 *= rs * kgm[1]; k2 *= rs * kgm[2]; k3 *= rs * kgm[3];
#pragma unroll
                for (int g = 0; g < 4; ++g) {
                    float sp = qn[g][0] * k0 + qn[g][1] * k1 + qn[g][2] * k2 + qn[g][3] * k3;
                    sp += __shfl_xor(sp, 1); sp += __shfl_xor(sp, 2);
                    sp += __shfl_xor(sp, 4); sp += __shfl_xor(sp, 8);
                    float scv = sp * 0.125f;                    // * hd^-0.5
                    float e2 = __expf(scv * (2.0f / SOFTCAP_));
                    float th = 1.0f - 2.0f / (e2 + 1.0f);       // tanh
                    float p = __expf(SOFTCAP_ * th);            // |capped|<=50, fp32-safe
                    denom[g] += p;
                    out_acc[g][0] += p * acc[mi][4][r];
                    out_acc[g][1] += p * acc[mi][5][r];
                    out_acc[g][2] += p * acc[mi][6][r];
                    out_acc[g][3] += p * acc[mi][7][r];
                }
            }
        }
    }
    // ---- combine: atomic add partial num/den (plain sums -> associative) ----
#pragma unroll
    for (int g = 0; g < 4; ++g) {
        float d = denom[g];
        d += __shfl_xor(d, 16); d += __shfl_xor(d, 32);
        if (l == 0) atomicAdd(den + bt * 16 + head * 4 + g, d);
#pragma unroll
        for (int ni = 0; ni < 4; ++ni) {
            float o = out_acc[g][ni];
            o += __shfl_xor(o, 16); o += __shfl_xor(o, 32);
            if (lg == 0)
                atomicAdd(att_raw + (size_t)bt * 1024 + (head * 4 + g) * 64 + ni * 16 + l15, o);
        }
    }
}

// ---------------- Output projection (divides by denominator during staging) ----------------
__global__ __launch_bounds__(256) void oproj_kernel(
    const float* __restrict__ att_raw, const float* __restrict__ den,
    const float* __restrict__ Wo, float* __restrict__ out)
{
    __shared__ float srows[8][1024];
    int cg = blockIdx.x, rg = blockIdx.y;
    int t = threadIdx.x;
#pragma unroll
    for (int j = 0; j < 8; ++j) {
        int f = j * 256 + t;
        int row = f >> 8, c4 = f & 255;
        float4 v = *(const float4*)(att_raw + (size_t)(rg * 8 + row) * 1024 + c4 * 4);
        float dv = den[(rg * 8 + row) * 16 + (c4 >> 4)];   // head = col/64 = c4/16
        float inv = 1.0f / dv;
        v.x *= inv; v.y *= inv; v.z *= inv; v.w *= inv;
        *(float4*)&srows[row][c4 * 4] = v;
    }
    __syncthreads();
    int c = cg * 64 + (t & 63);
    int rq = t >> 6;
    float acc0 = 0.f, acc1 = 0.f;
    for (int k = 0; k < 1024; k += 4) {
        float w0 = Wo[(size_t)(k + 0) * 1024 + c];
        float w1 = Wo[(size_t)(k + 1) * 1024 + c];
        float w2 = Wo[(size_t)(k + 2) * 1024 + c];
        float w3 = Wo[(size_t)(k + 3) * 1024 + c];
        float4 a0 = *(const float4*)&srows[rq * 2][k];
        float4 a1 = *(const float4*)&srows[rq * 2 + 1][k];
        acc0 += a0.x * w0 + a0.y * w1 + a0.z * w2 + a0.w * w3;
        acc1 += a1.x * w0 + a1.y * w1 + a1.z * w2 + a1.w * w3;
    }
    out[(size_t)(rg * 8 + rq * 2 + 0) * 1024 + c] = acc0;
    out[(size_t)(rg * 8 + rq * 2 + 1) * 1024 + c] = acc1;
}

extern "C" void kernel_launch(void* const* d_in, const int* in_sizes, int n_in,
                              void* d_out, int out_size, void* d_ws, size_t ws_size,
                              hipStream_t stream) {
    const float* agent = (const float*)d_in[0];
    const float* z     = (const float*)d_in[1];
    const float* Wq    = (const float*)d_in[2];
    const float* Wk    = (const float*)d_in[3];
    const float* Wv    = (const float*)d_in[4];
    const float* Wo    = (const float*)d_in[5];
    const float* qg    = (const float*)d_in[6];
    const float* kg    = (const float*)d_in[7];
    float* out = (float*)d_out;

    char* ws = (char*)d_ws;
    float* ws_q    = (float*)ws;                              // 2 MB
    float* att_raw = (float*)(ws + (2u << 20));               // 2 MB (unnormalized num)
    unsigned short* ws_wkv = (unsigned short*)(ws + (4u << 20)); // 1 MB
    float* den     = (float*)(ws + (5u << 20));               // 32 KB (512 x 16)

    hipMemsetAsync(att_raw, 0, 2u << 20, stream);
    hipMemsetAsync(den, 0, 512 * 16 * sizeof(float), stream);
    hipLaunchKernelGGL(wkv_swizzle, dim3(256), dim3(256), 0, stream, Wk, Wv, ws_wkv);
    hipLaunchKernelGGL(qproj_kernel, dim3(16, 64), dim3(256), 0, stream, agent, Wq, qg, ws_q);
    hipLaunchKernelGGL(kv_attn_kernel, dim3(2048), dim3(256), 0, stream, z, ws_wkv, ws_q, kg, att_raw, den);
    hipLaunchKernelGGL(oproj_kernel, dim3(16, 64), dim3(256), 0, stream, att_raw, den, Wo, out);
}

// Round 17
// 508.942 us; speedup vs baseline: 1.0633x; 1.0633x over previous
//
// Round 17: r16 with per-chunk atomic combine — out_acc/denom/qn are now
// EPILOGUE-LOCAL (nothing persists across the MFMA phase but kgm+addresses).
// r16 lesson: spill is a per-thread fixed cost; grid-2048 quadrupled it
// (WRITE 304 MB). r8 (the only spill-free run) proves small persistent state
// is what the allocator needs. Single-variable change vs r16.
#include <hip/hip_runtime.h>
#include <hip/hip_bf16.h>

#define SOFTCAP_ 50.0f
#define EPS_ 1e-6f

typedef __attribute__((ext_vector_type(8))) short bf16x8;
typedef __attribute__((ext_vector_type(4))) float f32x4;

__device__ __forceinline__ unsigned short f2bf(float f) {
    unsigned u = __float_as_uint(f);
    u += 0x7FFFu + ((u >> 16) & 1u);
    return (unsigned short)(u >> 16);
}

// ---------------- Wkv -> bf16 fragment-layout swizzle ----------------
// layout: [kb(32)][nb(32)][lane(64)][j(8)]  value = W'[kb*32+(l>>4)*8+j][nb*16+(l&15)]
// n<256 -> Wk col n ; n>=256 -> Wv col n-256
__global__ void wkv_swizzle(const float* __restrict__ Wk, const float* __restrict__ Wv,
                            unsigned short* __restrict__ wkv) {
    int tid = blockIdx.x * 256 + threadIdx.x;   // 0..65535
    int l = tid & 63;
    int nb = (tid >> 6) & 31;
    int kb = tid >> 11;
    int n = nb * 16 + (l & 15);
    int kbase = kb * 32 + ((l >> 4) << 3);
    const float* src = (n < 256) ? (Wk + n) : (Wv + (n - 256));
    unsigned short r[8];
#pragma unroll
    for (int j = 0; j < 8; ++j) r[j] = f2bf(src[(size_t)(kbase + j) * 256]);
    uint4 o;
    o.x = (unsigned)r[0] | ((unsigned)r[1] << 16);
    o.y = (unsigned)r[2] | ((unsigned)r[3] << 16);
    o.z = (unsigned)r[4] | ((unsigned)r[5] << 16);
    o.w = (unsigned)r[6] | ((unsigned)r[7] << 16);
    *(uint4*)(wkv + (size_t)tid * 8) = o;
}

// ---------------- Q projection + RMSNorm ----------------
__global__ __launch_bounds__(256) void qproj_kernel(
    const float* __restrict__ agent, const float* __restrict__ Wq,
    const float* __restrict__ q_gamma, float* __restrict__ ws_q)
{
    __shared__ float srows[8][1024];
    int cg = blockIdx.x, rg = blockIdx.y;
    int t = threadIdx.x;
#pragma unroll
    for (int j = 0; j < 8; ++j) {
        int f = j * 256 + t;
        int row = f >> 8, c4 = f & 255;
        *(float4*)&srows[row][c4 * 4] =
            *(const float4*)(agent + (size_t)(rg * 8 + row) * 1024 + c4 * 4);
    }
    __syncthreads();
    int c = cg * 64 + (t & 63);
    int rq = t >> 6;
    float acc0 = 0.f, acc1 = 0.f;
    for (int k = 0; k < 1024; k += 4) {
        float w0 = Wq[(size_t)(k + 0) * 1024 + c];
        float w1 = Wq[(size_t)(k + 1) * 1024 + c];
        float w2 = Wq[(size_t)(k + 2) * 1024 + c];
        float w3 = Wq[(size_t)(k + 3) * 1024 + c];
        float4 a0 = *(const float4*)&srows[rq * 2][k];
        float4 a1 = *(const float4*)&srows[rq * 2 + 1][k];
        acc0 += a0.x * w0 + a0.y * w1 + a0.z * w2 + a0.w * w3;
        acc1 += a1.x * w0 + a1.y * w1 + a1.z * w2 + a1.w * w3;
    }
    float g = q_gamma[t & 63];
    float ss0 = acc0 * acc0, ss1 = acc1 * acc1;
#pragma unroll
    for (int d = 1; d < 64; d <<= 1) { ss0 += __shfl_xor(ss0, d); ss1 += __shfl_xor(ss1, d); }
    float rs0 = rsqrtf(ss0 * (1.0f / 64.0f) + EPS_);
    float rs1 = rsqrtf(ss1 * (1.0f / 64.0f) + EPS_);
    ws_q[(size_t)(rg * 8 + rq * 2 + 0) * 1024 + c] = acc0 * rs0 * g;
    ws_q[(size_t)(rg * 8 + rq * 2 + 1) * 1024 + c] = acc1 * rs1 * g;
}

// ---------------- Fused KV projection + attention (grid 2048, per-chunk atomics) ----------------
// block = (bt, s-quarter of 64 rows); 4 waves = 4 kv-heads; wave does K scores AND V
// for its head over 2 sub-chunks of 32 rows. All softmax state is chunk-local;
// partial num/den atomicAdd'ed per chunk (softcap => plain sums, associative).
__global__ __launch_bounds__(256, 3) void kv_attn_kernel(
    const float* __restrict__ z, const unsigned short* __restrict__ wkv,
    const float* __restrict__ ws_q, const float* __restrict__ k_gamma,
    float* __restrict__ att_raw, float* __restrict__ den)
{
    __shared__ __align__(16) unsigned short zlds[32 * 256];   // 16 KB, XOR-swizzled bf16
    const int blk = blockIdx.x;
    const int bt = blk >> 2, q = blk & 3;  // s-quarter q: rows bt*256 + q*64 ..
    const int tid = threadIdx.x;
    const int head = tid >> 6;             // wave = kv head 0..3
    const int l = tid & 63, l15 = l & 15, lg = l >> 4;

    float kgm[4];
#pragma unroll
    for (int ni = 0; ni < 4; ++ni) kgm[ni] = k_gamma[ni * 16 + l15];

    for (int sc = 0; sc < 2; ++sc) {       // 2 sub-chunks of 32 s-rows
        f32x4 acc[2][8];
#pragma unroll
        for (int mi = 0; mi < 2; ++mi)
#pragma unroll
            for (int ni = 0; ni < 8; ++ni) acc[mi][ni] = (f32x4){0.f, 0.f, 0.f, 0.f};

        for (int sl = 0; sl < 4; ++sl) {   // k-slices of 256
            __syncthreads();               // prior reads of zlds done
#pragma unroll
            for (int jb = 0; jb < 2; ++jb) {   // stage 32x256 fp32 -> bf16 (8 float4/thr)
                float4 v[4];
#pragma unroll
                for (int i = 0; i < 4; ++i) {
                    int f = (jb * 4 + i) * 256 + tid;   // float4 idx 0..2047
                    int row = f >> 6, c4 = f & 63;
                    v[i] = *(const float4*)(z + (size_t)(bt * 256 + q * 64 + sc * 32 + row) * 1024
                                              + sl * 256 + c4 * 4);
                }
#pragma unroll
                for (int i = 0; i < 4; ++i) {
                    int f = (jb * 4 + i) * 256 + tid;
                    int row = f >> 6, c4 = f & 63;
                    unsigned lo = (unsigned)f2bf(v[i].x) | ((unsigned)f2bf(v[i].y) << 16);
                    unsigned hi = (unsigned)f2bf(v[i].z) | ((unsigned)f2bf(v[i].w) << 16);
                    int byteoff = ((row * 512) + c4 * 8) ^ ((row & 7) << 4);
                    *(uint2*)((char*)zlds + byteoff) = (uint2){lo, hi};
                }
            }
            __syncthreads();               // stage visible
#pragma unroll
            for (int ksl = 0; ksl < 8; ++ksl) {
                const int kb = sl * 8 + ksl;
                int boff0 = ((l15 * 512) + ksl * 64 + lg * 16) ^ ((l15 & 7) << 4);
                bf16x8 a0 = *(const bf16x8*)((const char*)zlds + boff0);
                bf16x8 a1 = *(const bf16x8*)((const char*)zlds + boff0 + 8192); // row+16: same swizzle
                // K group then V group: peak live b = 4
                bf16x8 bk[4];
#pragma unroll
                for (int ni = 0; ni < 4; ++ni)
                    bk[ni] = *(const bf16x8*)(wkv + ((size_t)(kb * 32 + head * 4 + ni) * 64 + l) * 8);
#pragma unroll
                for (int ni = 0; ni < 4; ++ni) {
                    acc[0][ni] = __builtin_amdgcn_mfma_f32_16x16x32_bf16(a0, bk[ni], acc[0][ni], 0, 0, 0);
                    acc[1][ni] = __builtin_amdgcn_mfma_f32_16x16x32_bf16(a1, bk[ni], acc[1][ni], 0, 0, 0);
                }
                bf16x8 bv[4];
#pragma unroll
                for (int ni = 0; ni < 4; ++ni)
                    bv[ni] = *(const bf16x8*)(wkv + ((size_t)(kb * 32 + 16 + head * 4 + ni) * 64 + l) * 8);
#pragma unroll
                for (int ni = 0; ni < 4; ++ni) {
                    acc[0][4 + ni] = __builtin_amdgcn_mfma_f32_16x16x32_bf16(a0, bv[ni], acc[0][4 + ni], 0, 0, 0);
                    acc[1][4 + ni] = __builtin_amdgcn_mfma_f32_16x16x32_bf16(a1, bv[ni], acc[1][4 + ni], 0, 0, 0);
                }
            }
        }
        // ---- epilogue: ALL state chunk-local (qn, oa, dn) ----
        float qn[4][4];
#pragma unroll
        for (int g = 0; g < 4; ++g)
#pragma unroll
            for (int ni = 0; ni < 4; ++ni)
                qn[g][ni] = ws_q[(size_t)bt * 1024 + (head * 4 + g) * 64 + ni * 16 + l15];
        float oa[4][4] = {};
        float dn[4] = {};
#pragma unroll
        for (int mi = 0; mi < 2; ++mi) {
#pragma unroll
            for (int r = 0; r < 4; ++r) {
                float k0 = acc[mi][0][r], k1 = acc[mi][1][r], k2 = acc[mi][2][r], k3 = acc[mi][3][r];
                float ss = k0 * k0 + k1 * k1 + k2 * k2 + k3 * k3;
                ss += __shfl_xor(ss, 1); ss += __shfl_xor(ss, 2);
                ss += __shfl_xor(ss, 4); ss += __shfl_xor(ss, 8);
                float rs = rsqrtf(ss * (1.0f / 64.0f) + EPS_);
                k0 *= rs * kgm[0]; k1 *= rs * kgm[1]; k2 *= rs * kgm[2]; k3 *= rs * kgm[3];
#pragma unroll
                for (int g = 0; g < 4; ++g) {
                    float sp = qn[g][0] * k0 + qn[g][1] * k1 + qn[g][2] * k2 + qn[g][3] * k3;
                    sp += __shfl_xor(sp, 1); sp += __shfl_xor(sp, 2);
                    sp += __shfl_xor(sp, 4); sp += __shfl_xor(sp, 8);
                    float scv = sp * 0.125f;                    // * hd^-0.5
                    float e2 = __expf(scv * (2.0f / SOFTCAP_));
                    float th = 1.0f - 2.0f / (e2 + 1.0f);       // tanh
                    float p = __expf(SOFTCAP_ * th);            // |capped|<=50, fp32-safe
                    dn[g] += p;
                    oa[g][0] += p * acc[mi][4][r];
                    oa[g][1] += p * acc[mi][5][r];
                    oa[g][2] += p * acc[mi][6][r];
                    oa[g][3] += p * acc[mi][7][r];
                }
            }
        }
        // ---- per-chunk combine: atomic add partial num/den ----
#pragma unroll
        for (int g = 0; g < 4; ++g) {
            float d = dn[g];
            d += __shfl_xor(d, 16); d += __shfl_xor(d, 32);
            if (l == 0) atomicAdd(den + bt * 16 + head * 4 + g, d);
#pragma unroll
            for (int ni = 0; ni < 4; ++ni) {
                float o = oa[g][ni];
                o += __shfl_xor(o, 16); o += __shfl_xor(o, 32);
                if (lg == 0)
                    atomicAdd(att_raw + (size_t)bt * 1024 + (head * 4 + g) * 64 + ni * 16 + l15, o);
            }
        }
    }
}

// ---------------- Output projection (divides by denominator during staging) ----------------
__global__ __launch_bounds__(256) void oproj_kernel(
    const float* __restrict__ att_raw, const float* __restrict__ den,
    const float* __restrict__ Wo, float* __restrict__ out)
{
    __shared__ float srows[8][1024];
    int cg = blockIdx.x, rg = blockIdx.y;
    int t = threadIdx.x;
#pragma unroll
    for (int j = 0; j < 8; ++j) {
        int f = j * 256 + t;
        int row = f >> 8, c4 = f & 255;
        float4 v = *(const float4*)(att_raw + (size_t)(rg * 8 + row) * 1024 + c4 * 4);
        float dv = den[(rg * 8 + row) * 16 + (c4 >> 4)];   // head = col/64 = c4/16
        float inv = 1.0f / dv;
        v.x *= inv; v.y *= inv; v.z *= inv; v.w *= inv;
        *(float4*)&srows[row][c4 * 4] = v;
    }
    __syncthreads();
    int c = cg * 64 + (t & 63);
    int rq = t >> 6;
    float acc0 = 0.f, acc1 = 0.f;
    for (int k = 0; k < 1024; k += 4) {
        float w0 = Wo[(size_t)(k + 0) * 1024 + c];
        float w1 = Wo[(size_t)(k + 1) * 1024 + c];
        float w2 = Wo[(size_t)(k + 2) * 1024 + c];
        float w3 = Wo[(size_t)(k + 3) * 1024 + c];
        float4 a0 = *(const float4*)&srows[rq * 2][k];
        float4 a1 = *(const float4*)&srows[rq * 2 + 1][k];
        acc0 += a0.x * w0 + a0.y * w1 + a0.z * w2 + a0.w * w3;
        acc1 += a1.x * w0 + a1.y * w1 + a1.z * w2 + a1.w * w3;
    }
    out[(size_t)(rg * 8 + rq * 2 + 0) * 1024 + c] = acc0;
    out[(size_t)(rg * 8 + rq * 2 + 1) * 1024 + c] = acc1;
}

extern "C" void kernel_launch(void* const* d_in, const int* in_sizes, int n_in,
                              void* d_out, int out_size, void* d_ws, size_t ws_size,
                              hipStream_t stream) {
    const float* agent = (const float*)d_in[0];
    const float* z     = (const float*)d_in[1];
    const float* Wq    = (const float*)d_in[2];
    const float* Wk    = (const float*)d_in[3];
    const float* Wv    = (const float*)d_in[4];
    const float* Wo    = (const float*)d_in[5];
    const float* qg    = (const float*)d_in[6];
    const float* kg    = (const float*)d_in[7];
    float* out = (float*)d_out;

    char* ws = (char*)d_ws;
    float* ws_q    = (float*)ws;                              // 2 MB
    float* att_raw = (float*)(ws + (2u << 20));               // 2 MB (unnormalized num)
    unsigned short* ws_wkv = (unsigned short*)(ws + (4u << 20)); // 1 MB
    float* den     = (float*)(ws + (5u << 20));               // 32 KB (512 x 16)

    hipMemsetAsync(att_raw, 0, 2u << 20, stream);
    hipMemsetAsync(den, 0, 512 * 16 * sizeof(float), stream);
    hipLaunchKernelGGL(wkv_swizzle, dim3(256), dim3(256), 0, stream, Wk, Wv, ws_wkv);
    hipLaunchKernelGGL(qproj_kernel, dim3(16, 64), dim3(256), 0, stream, agent, Wq, qg, ws_q);
    hipLaunchKernelGGL(kv_attn_kernel, dim3(2048), dim3(256), 0, stream, z, ws_wkv, ws_q, kg, att_raw, den);
    hipLaunchKernelGGL(oproj_kernel, dim3(16, 64), dim3(256), 0, stream, att_raw, den, Wo, out);
}